// Round 4
// baseline (76.279 us; speedup 1.0000x reference)
//
#include <hip/hip_runtime.h>
#include <hip/hip_bf16.h>

// Problem constants
#define BB 64
#define LL 4096
#define CC 16
#define PL 128
#define PC 8
#define NPP 64
#define DD 64
#define TSTEP 0.01f

#define PPB 16                      // patches per block (M tile)
#define KSPLIT 8                    // lt-range split across blocks
#define LT_PER (PL / KSPLIT)        // 16 lt steps per block
#define NT_MAIN 256                 // 4 waves; wave = one 16-wide N-slice
#define XSTRIDE 12                  // xvbuf patch stride in floats (48B, conflict-free)

typedef float f32x4 __attribute__((ext_vector_type(4)));
typedef int   i32x4 __attribute__((ext_vector_type(4)));
typedef unsigned int u32;

__device__ __forceinline__ u32 f2bf(float f) {          // fp32 -> bf16 bits, RNE
    u32 u = __float_as_uint(f);
    return (u + 0x7fffu + ((u >> 16) & 1u)) >> 16;
}
__device__ __forceinline__ float silu_f(float z) {      // z * rcp(1+exp(-z))
    return z * __builtin_amdgcn_rcpf(1.0f + __expf(-z));
}
__device__ __forceinline__ u32 pack_bf16(float lo, float hi) {
    __hip_bfloat162 p = __float22bfloat162_rn(float2{lo, hi});
    u32 r;
    __builtin_memcpy(&r, &p, 4);
    return r;
}

// ---------- W3 (8192x64 f32) -> bf16 MFMA B-fragments in ws (1 MB) ----------
// frag id m = (lt*2 + kk)*4 + ns ; lane holds W3[kb + (lane>>4)*8 + j][ns*16 + (lane&15)]
__global__ __launch_bounds__(256) void w3_prep(const float* __restrict__ W3,
                                               u32* __restrict__ wsf) {
    const int tid  = blockIdx.x * 256 + threadIdx.x;    // 65536 threads
    const int lane = tid & 63;
    const int m    = tid >> 6;                          // 0..1023
    const int ns   = m & 3;
    const int kb   = (m >> 2) * 32;                     // lt*64 + kk*32
    const int row0 = kb + ((lane >> 4) << 3);
    const int col  = (ns << 4) + (lane & 15);
    u32 q[4];
    #pragma unroll
    for (int jj = 0; jj < 4; ++jj) {
        const float lo = W3[(size_t)(row0 + 2 * jj)     * DD + col];
        const float hi = W3[(size_t)(row0 + 2 * jj + 1) * DD + col];
        q[jj] = f2bf(lo) | (f2bf(hi) << 16);
    }
    i32x4 v; v.x = q[0]; v.y = q[1]; v.z = q[2]; v.w = q[3];
    *(i32x4*)(wsf + (size_t)m * 256 + (lane << 2)) = v;
}

// ---------------------------- fused main kernel ----------------------------
template<bool USE_WS>
__global__ __launch_bounds__(NT_MAIN, 8) void htfe_main(
    const float* __restrict__ x, const int* __restrict__ start_L,
    const int* __restrict__ idx_C, const float* __restrict__ W1,
    const float* __restrict__ b1, const float* __restrict__ W3,
    const u32* __restrict__ wsf, float* __restrict__ out)
{
    __shared__ __align__(16) float xvbuf[LT_PER][PPB * XSTRIDE]; // 12 KB gathered x
    __shared__ __align__(16) u32   hbuf[2][PPB * DD / 2];        // 2x2 KB bf16 h, swizzled
    __shared__ int sStart[PPB];
    __shared__ int sCi[PPB][PC];

    const int t    = threadIdx.x;
    const int lane = t & 63;
    const int w    = t >> 6;                 // wave = N-slice 0..3
    const int blk  = blockIdx.x;
    const int split = blk & (KSPLIT - 1);
    const int mb    = blk >> 3;              // /KSPLIT
    const int b     = mb >> 2;               // NPP/PPB = 4 groups
    const int p0    = (mb & 3) * PPB;
    const int lt0   = split * LT_PER;

    if (t < PPB) sStart[t] = start_L[b * NPP + p0 + t];
    if (t < PPB * PC) {
        const int pp = t >> 3, c = t & 7;
        sCi[pp][c] = idx_C[(size_t)((b * NPP + p0 + pp) << 3) + c];
    }
    __syncthreads();

    // ----- per-lane hoisted W1 slice + folded constant bias -----
    const int p  = lane >> 2;                       // phase-A patch
    const int d0 = (w << 4) + ((lane & 3) << 2);    // phase-A d base (4 values)
    float w1x[PC][4], w1t[4], cb[4];
    {
        const f32x4 vt = *(const f32x4*)(W1 + PC * DD + d0);
        const f32x4 vb = *(const f32x4*)(b1 + d0);
        const float st = (float)sStart[p] * TSTEP;  // start never wraps: start <= L-PL
        #pragma unroll
        for (int j = 0; j < 4; ++j) { w1t[j] = vt[j]; cb[j] = vb[j] + st * vt[j]; }
        #pragma unroll
        for (int c = 0; c < PC; ++c) {
            const f32x4 vx = *(const f32x4*)(W1 + c * DD + d0);
            const f32x4 vc = *(const f32x4*)(W1 + (PC + 1 + c) * DD + d0);
            const float cf = (float)sCi[p][c];
            #pragma unroll
            for (int j = 0; j < 4; ++j) { w1x[c][j] = vx[j]; cb[j] += cf * vc[j]; }
        }
    }

    // ----- stage all gathered x values for this block's lt range -----
    for (int i = t; i < LT_PER * PPB * PC; i += NT_MAIN) {
        const int lt = i >> 7;
        const int pp = (i >> 3) & 15;
        const int c  = i & 7;
        xvbuf[lt][pp * XSTRIDE + c] =
            x[((size_t)b * LL + (size_t)(sStart[pp] + lt0 + lt)) * CC + sCi[pp][c]];
    }
    __syncthreads();

    // swizzled LDS addresses: byte = (p*128 + d*2) ^ ((p&7)<<4)
    const int wrByte = ((p << 7) + (d0 << 1)) ^ ((p & 7) << 4);
    const int pB    = lane & 15;
    const int rbase = (pB << 7) + ((lane >> 4) << 4);
    const int swzB  = (pB & 7) << 4;
    const int rd0 = rbase ^ swzB;
    const int rd1 = (rbase + 64) ^ swzB;

    f32x4 acc = {0.f, 0.f, 0.f, 0.f};
    const u32* bsrc = wsf + (size_t)(lt0 * 8 + w) * 256 + (lane << 2);

    for (int lt = 0; lt < LT_PER; ++lt) {
        const int cur = lt & 1;
        // ---- phase A: 4 h values per lane (9 fma + cheap silu, all-register) ----
        const float tl = (float)(lt0 + lt) * TSTEP;
        const float* xvp = &xvbuf[lt][p * XSTRIDE];
        const f32x4 xa = *(const f32x4*)xvp;
        const f32x4 xc = *(const f32x4*)(xvp + 4);
        float hh[4];
        #pragma unroll
        for (int j = 0; j < 4; ++j) {
            float a = cb[j] + tl * w1t[j];
            a += xa.x * w1x[0][j]; a += xa.y * w1x[1][j];
            a += xa.z * w1x[2][j]; a += xa.w * w1x[3][j];
            a += xc.x * w1x[4][j]; a += xc.y * w1x[5][j];
            a += xc.z * w1x[6][j]; a += xc.w * w1x[7][j];
            hh[j] = silu_f(a);
        }
        const u32 pk0 = pack_bf16(hh[0], hh[1]);
        const u32 pk1 = pack_bf16(hh[2], hh[3]);
        char* hbB = (char*)&hbuf[cur][0];
        *(uint2*)(hbB + wrByte) = make_uint2(pk0, pk1);

        // ---- B-fragments (issued before the barrier to hide latency) ----
        i32x4 bf0, bf1;
        if (USE_WS) {
            bf0 = *(const i32x4*)(bsrc);
            bf1 = *(const i32x4*)(bsrc + 1024);
            bsrc += 2048;
        } else {
            const int row0 = (lt0 + lt) * DD + ((lane >> 4) << 3);
            const int colW = (w << 4) + pB;
            u32 q[8];
            #pragma unroll
            for (int jj = 0; jj < 4; ++jj) {
                q[jj]     = f2bf(W3[(size_t)(row0 + 2*jj)      * DD + colW]) |
                            (f2bf(W3[(size_t)(row0 + 2*jj + 1) * DD + colW]) << 16);
                q[4 + jj] = f2bf(W3[(size_t)(row0 + 32 + 2*jj)      * DD + colW]) |
                            (f2bf(W3[(size_t)(row0 + 32 + 2*jj + 1) * DD + colW]) << 16);
            }
            bf0.x = q[0]; bf0.y = q[1]; bf0.z = q[2]; bf0.w = q[3];
            bf1.x = q[4]; bf1.y = q[5]; bf1.z = q[6]; bf1.w = q[7];
        }

        __syncthreads();   // h tile ready (double-buffered -> 1 barrier per lt)

        // ---- phase B: A-frags from swizzled LDS, 2 MFMAs ----
        const i32x4 af0 = *(const i32x4*)(hbB + rd0);
        const i32x4 af1 = *(const i32x4*)(hbB + rd1);
        if (!USE_WS) asm volatile("s_nop 3" ::);   // VALU-write -> MFMA-read hazard
        asm("v_mfma_f32_16x16x32_bf16 %0, %1, %2, %0" : "+v"(acc) : "v"(af0), "v"(bf0));
        asm("v_mfma_f32_16x16x32_bf16 %0, %1, %2, %0" : "+v"(acc) : "v"(af1), "v"(bf1));
    }

    asm volatile("s_nop 7\ns_nop 7\ns_nop 7" ::);  // MFMA-write -> VMEM-read hazard
    #pragma unroll
    for (int r = 0; r < 4; ++r) {
        const int prow = ((lane >> 4) << 2) + r;   // verified C/D layout (m89/m91)
        atomicAdd(out + (size_t)(b * NPP + p0 + prow) * DD + (w << 4) + pB, acc[r]);
    }
}

// --------------------------- bias + SiLU epilogue ---------------------------
__global__ __launch_bounds__(256) void finish_silu(float* __restrict__ out,
                                                   const float* __restrict__ b3) {
    const int i = blockIdx.x * 256 + threadIdx.x;   // 65536 threads x 4 elems
    const int base = i << 2;
    f32x4 v = *(f32x4*)(out + base);
    const f32x4 bb = *(const f32x4*)(b3 + (base & 63));
    #pragma unroll
    for (int j = 0; j < 4; ++j) v[j] = silu_f(v[j] + bb[j]);
    *(f32x4*)(out + base) = v;
}

extern "C" void kernel_launch(void* const* d_in, const int* in_sizes, int n_in,
                              void* d_out, int out_size, void* d_ws, size_t ws_size,
                              hipStream_t stream) {
    // inputs: x, start_L, idx_C, W1, b1, W2(unused), b2(unused), W3, b3
    const float* x       = (const float*)d_in[0];
    const int*   start_L = (const int*)  d_in[1];
    const int*   idx_C   = (const int*)  d_in[2];
    const float* W1      = (const float*)d_in[3];
    const float* b1      = (const float*)d_in[4];
    const float* W3      = (const float*)d_in[7];
    const float* b3      = (const float*)d_in[8];
    float* out = (float*)d_out;
    u32*   wsf = (u32*)d_ws;

    (void)hipMemsetAsync(d_out, 0, (size_t)out_size * sizeof(float), stream);

    const int grid_main = BB * (NPP / PPB) * KSPLIT;   // 2048
    const bool use_ws = ws_size >= (size_t)(PL * 2 * 4) * 1024;   // 1 MB of frags
    if (use_ws) {
        w3_prep<<<256, 256, 0, stream>>>(W3, wsf);
        htfe_main<true><<<grid_main, NT_MAIN, 0, stream>>>(
            x, start_L, idx_C, W1, b1, W3, wsf, out);
    } else {
        htfe_main<false><<<grid_main, NT_MAIN, 0, stream>>>(
            x, start_L, idx_C, W1, b1, W3, wsf, out);
    }
    finish_silu<<<(BB * NPP * DD / 4) / 256, 256, 0, stream>>>(out, b3);
}

// Round 5
// 39.921 us; speedup vs baseline: 1.9108x; 1.9108x over previous
//
#include <hip/hip_runtime.h>
#include <hip/hip_bf16.h>

// Problem constants
#define BB 64
#define LL 4096
#define CC 16
#define PL 128
#define PC 8
#define NPP 64
#define DD 64
#define TSTEP 0.01f

#define PPB 16                      // patches per block (M tile)
#define KSPLIT 8                    // lt-range split across blocks
#define LT_PER (PL / KSPLIT)        // 16 lt steps per block
#define NT_MAIN 256                 // 4 waves; wave = one 16-wide N-slice
#define XSTRIDE 12                  // xvbuf patch stride in floats (48B, conflict-free)

typedef float f32x4 __attribute__((ext_vector_type(4)));
typedef int   i32x4 __attribute__((ext_vector_type(4)));
typedef unsigned int u32;

__device__ __forceinline__ u32 f2bf(float f) {          // fp32 -> bf16 bits, RNE
    u32 u = __float_as_uint(f);
    return (u + 0x7fffu + ((u >> 16) & 1u)) >> 16;
}
__device__ __forceinline__ float silu_f(float z) {      // z * rcp(1+exp(-z))
    return z * __builtin_amdgcn_rcpf(1.0f + __expf(-z));
}
__device__ __forceinline__ u32 pack_bf16(float lo, float hi) {
    __hip_bfloat162 p = __float22bfloat162_rn(float2{lo, hi});
    u32 r;
    __builtin_memcpy(&r, &p, 4);
    return r;
}

// ---------- W3 (8192x64 f32) -> bf16 MFMA B-fragments in ws (1 MB) ----------
// frag id m = (lt*2 + kk)*4 + ns ; lane holds W3[kb + (lane>>4)*8 + j][ns*16 + (lane&15)]
__global__ __launch_bounds__(256) void w3_prep(const float* __restrict__ W3,
                                               u32* __restrict__ wsf) {
    const int tid  = blockIdx.x * 256 + threadIdx.x;    // 65536 threads
    const int lane = tid & 63;
    const int m    = tid >> 6;                          // 0..1023
    const int ns   = m & 3;
    const int kb   = (m >> 2) * 32;                     // lt*64 + kk*32
    const int row0 = kb + ((lane >> 4) << 3);
    const int col  = (ns << 4) + (lane & 15);
    u32 q[4];
    #pragma unroll
    for (int jj = 0; jj < 4; ++jj) {
        const float lo = W3[(size_t)(row0 + 2 * jj)     * DD + col];
        const float hi = W3[(size_t)(row0 + 2 * jj + 1) * DD + col];
        q[jj] = f2bf(lo) | (f2bf(hi) << 16);
    }
    i32x4 v; v.x = q[0]; v.y = q[1]; v.z = q[2]; v.w = q[3];
    *(i32x4*)(wsf + (size_t)m * 256 + (lane << 2)) = v;
}

// ---------------------------- fused main kernel ----------------------------
// NOTE: no min-waves hint — __launch_bounds__(256, 8) forced the ~40-float W1
// state into scratch (round 4: WRITE_SIZE 4->90 MB, VALUBusy 49->21%).
template<bool USE_WS>
__global__ __launch_bounds__(NT_MAIN) void htfe_main(
    const float* __restrict__ x, const int* __restrict__ start_L,
    const int* __restrict__ idx_C, const float* __restrict__ W1,
    const float* __restrict__ b1, const float* __restrict__ W3,
    const u32* __restrict__ wsf, float* __restrict__ out)
{
    __shared__ __align__(16) float xvbuf[LT_PER][PPB * XSTRIDE]; // 12 KB gathered x
    __shared__ __align__(16) u32   hbuf[2][PPB * DD / 2];        // 2x2 KB bf16 h, swizzled
    __shared__ int sStart[PPB];
    __shared__ int sCi[PPB][PC];

    const int t    = threadIdx.x;
    const int lane = t & 63;
    const int w    = t >> 6;                 // wave = N-slice 0..3
    const int blk  = blockIdx.x;
    const int split = blk & (KSPLIT - 1);
    const int mb    = blk >> 3;              // /KSPLIT
    const int b     = mb >> 2;               // NPP/PPB = 4 groups
    const int p0    = (mb & 3) * PPB;
    const int lt0   = split * LT_PER;

    if (t < PPB) sStart[t] = start_L[b * NPP + p0 + t];
    if (t < PPB * PC) {
        const int pp = t >> 3, c = t & 7;
        sCi[pp][c] = idx_C[(size_t)((b * NPP + p0 + pp) << 3) + c];
    }
    __syncthreads();

    // ----- per-lane hoisted W1 slice + folded constant bias -----
    const int p  = lane >> 2;                       // phase-A patch
    const int d0 = (w << 4) + ((lane & 3) << 2);    // phase-A d base (4 values)
    float w1x[PC][4], w1t[4], cb[4];
    {
        const f32x4 vt = *(const f32x4*)(W1 + PC * DD + d0);
        const f32x4 vb = *(const f32x4*)(b1 + d0);
        const float st = (float)sStart[p] * TSTEP;  // start never wraps: start <= L-PL
        #pragma unroll
        for (int j = 0; j < 4; ++j) { w1t[j] = vt[j]; cb[j] = vb[j] + st * vt[j]; }
        #pragma unroll
        for (int c = 0; c < PC; ++c) {
            const f32x4 vx = *(const f32x4*)(W1 + c * DD + d0);
            const f32x4 vc = *(const f32x4*)(W1 + (PC + 1 + c) * DD + d0);
            const float cf = (float)sCi[p][c];
            #pragma unroll
            for (int j = 0; j < 4; ++j) { w1x[c][j] = vx[j]; cb[j] += cf * vc[j]; }
        }
    }

    // ----- stage all gathered x values for this block's lt range -----
    for (int i = t; i < LT_PER * PPB * PC; i += NT_MAIN) {
        const int lt = i >> 7;
        const int pp = (i >> 3) & 15;
        const int c  = i & 7;
        xvbuf[lt][pp * XSTRIDE + c] =
            x[((size_t)b * LL + (size_t)(sStart[pp] + lt0 + lt)) * CC + sCi[pp][c]];
    }
    __syncthreads();

    // swizzled LDS addresses: byte = (p*128 + d*2) ^ ((p&7)<<4)
    const int wrByte = ((p << 7) + (d0 << 1)) ^ ((p & 7) << 4);
    const int pB    = lane & 15;
    const int rbase = (pB << 7) + ((lane >> 4) << 4);
    const int swzB  = (pB & 7) << 4;
    const int rd0 = rbase ^ swzB;
    const int rd1 = (rbase + 64) ^ swzB;

    f32x4 acc = {0.f, 0.f, 0.f, 0.f};
    const u32* bsrc = wsf + (size_t)(lt0 * 8 + w) * 256 + (lane << 2);

    for (int lt = 0; lt < LT_PER; ++lt) {
        const int cur = lt & 1;
        // ---- phase A: 4 h values per lane (9 fma + cheap silu, all-register) ----
        const float tl = (float)(lt0 + lt) * TSTEP;
        const float* xvp = &xvbuf[lt][p * XSTRIDE];
        const f32x4 xa = *(const f32x4*)xvp;
        const f32x4 xc = *(const f32x4*)(xvp + 4);
        float hh[4];
        #pragma unroll
        for (int j = 0; j < 4; ++j) {
            float a = cb[j] + tl * w1t[j];
            a += xa.x * w1x[0][j]; a += xa.y * w1x[1][j];
            a += xa.z * w1x[2][j]; a += xa.w * w1x[3][j];
            a += xc.x * w1x[4][j]; a += xc.y * w1x[5][j];
            a += xc.z * w1x[6][j]; a += xc.w * w1x[7][j];
            hh[j] = silu_f(a);
        }
        const u32 pk0 = pack_bf16(hh[0], hh[1]);
        const u32 pk1 = pack_bf16(hh[2], hh[3]);
        char* hbB = (char*)&hbuf[cur][0];
        *(uint2*)(hbB + wrByte) = make_uint2(pk0, pk1);

        // ---- B-fragments (issued before the barrier to hide latency) ----
        i32x4 bf0, bf1;
        if (USE_WS) {
            bf0 = *(const i32x4*)(bsrc);
            bf1 = *(const i32x4*)(bsrc + 1024);
            bsrc += 2048;
        } else {
            const int row0 = (lt0 + lt) * DD + ((lane >> 4) << 3);
            const int colW = (w << 4) + pB;
            u32 q[8];
            #pragma unroll
            for (int jj = 0; jj < 4; ++jj) {
                q[jj]     = f2bf(W3[(size_t)(row0 + 2*jj)      * DD + colW]) |
                            (f2bf(W3[(size_t)(row0 + 2*jj + 1) * DD + colW]) << 16);
                q[4 + jj] = f2bf(W3[(size_t)(row0 + 32 + 2*jj)      * DD + colW]) |
                            (f2bf(W3[(size_t)(row0 + 32 + 2*jj + 1) * DD + colW]) << 16);
            }
            bf0.x = q[0]; bf0.y = q[1]; bf0.z = q[2]; bf0.w = q[3];
            bf1.x = q[4]; bf1.y = q[5]; bf1.z = q[6]; bf1.w = q[7];
        }

        __syncthreads();   // h tile ready (double-buffered -> 1 barrier per lt)

        // ---- phase B: A-frags from swizzled LDS, 2 MFMAs ----
        const i32x4 af0 = *(const i32x4*)(hbB + rd0);
        const i32x4 af1 = *(const i32x4*)(hbB + rd1);
        if (!USE_WS) asm volatile("s_nop 3" ::);   // VALU-write -> MFMA-read hazard
        asm("v_mfma_f32_16x16x32_bf16 %0, %1, %2, %0" : "+v"(acc) : "v"(af0), "v"(bf0));
        asm("v_mfma_f32_16x16x32_bf16 %0, %1, %2, %0" : "+v"(acc) : "v"(af1), "v"(bf1));
    }

    asm volatile("s_nop 7\ns_nop 7\ns_nop 7" ::);  // MFMA-write -> VMEM-read hazard
    #pragma unroll
    for (int r = 0; r < 4; ++r) {
        const int prow = ((lane >> 4) << 2) + r;   // verified C/D layout (m89/m91)
        atomicAdd(out + (size_t)(b * NPP + p0 + prow) * DD + (w << 4) + pB, acc[r]);
    }
}

// --------------------------- bias + SiLU epilogue ---------------------------
__global__ __launch_bounds__(256) void finish_silu(float* __restrict__ out,
                                                   const float* __restrict__ b3) {
    const int i = blockIdx.x * 256 + threadIdx.x;   // 65536 threads x 4 elems
    const int base = i << 2;
    f32x4 v = *(f32x4*)(out + base);
    const f32x4 bb = *(const f32x4*)(b3 + (base & 63));
    #pragma unroll
    for (int j = 0; j < 4; ++j) v[j] = silu_f(v[j] + bb[j]);
    *(f32x4*)(out + base) = v;
}

extern "C" void kernel_launch(void* const* d_in, const int* in_sizes, int n_in,
                              void* d_out, int out_size, void* d_ws, size_t ws_size,
                              hipStream_t stream) {
    // inputs: x, start_L, idx_C, W1, b1, W2(unused), b2(unused), W3, b3
    const float* x       = (const float*)d_in[0];
    const int*   start_L = (const int*)  d_in[1];
    const int*   idx_C   = (const int*)  d_in[2];
    const float* W1      = (const float*)d_in[3];
    const float* b1      = (const float*)d_in[4];
    const float* W3      = (const float*)d_in[7];
    const float* b3      = (const float*)d_in[8];
    float* out = (float*)d_out;
    u32*   wsf = (u32*)d_ws;

    (void)hipMemsetAsync(d_out, 0, (size_t)out_size * sizeof(float), stream);

    const int grid_main = BB * (NPP / PPB) * KSPLIT;   // 2048
    const bool use_ws = ws_size >= (size_t)(PL * 2 * 4) * 1024;   // 1 MB of frags
    if (use_ws) {
        w3_prep<<<256, 256, 0, stream>>>(W3, wsf);
        htfe_main<true><<<grid_main, NT_MAIN, 0, stream>>>(
            x, start_L, idx_C, W1, b1, W3, wsf, out);
    } else {
        htfe_main<false><<<grid_main, NT_MAIN, 0, stream>>>(
            x, start_L, idx_C, W1, b1, W3, wsf, out);
    }
    finish_silu<<<(BB * NPP * DD / 4) / 256, 256, 0, stream>>>(out, b3);
}

// Round 6
// 39.137 us; speedup vs baseline: 1.9490x; 1.0200x over previous
//
#include <hip/hip_runtime.h>
#include <hip/hip_bf16.h>

// Problem constants
#define BB 64
#define LL 4096
#define CC 16
#define PL 128
#define PC 8
#define NPP 64
#define DD 64
#define TSTEP 0.01f

#define PPB 16                      // patches per block (M tile)
#define KSPLIT 8                    // lt-range split across blocks
#define LT_PER (PL / KSPLIT)        // 16 lt steps per block
#define NT_MAIN 256                 // 4 waves; wave = one 16-wide N-slice
#define XSTRIDE 12                  // xvbuf patch stride in floats (48B, conflict-free)

#define FRAG_U32  (PL * 2 * 4 * 256)            // 262144 u32 = 1 MB of W3 frags
#define PART_FLT  (BB * 4 * KSPLIT * 4 * 256)   // 2M floats = 8 MB of partials

typedef float f32x4 __attribute__((ext_vector_type(4)));
typedef int   i32x4 __attribute__((ext_vector_type(4)));
typedef unsigned int u32;

__device__ __forceinline__ u32 f2bf(float f) {          // fp32 -> bf16 bits, RNE
    u32 u = __float_as_uint(f);
    return (u + 0x7fffu + ((u >> 16) & 1u)) >> 16;
}
__device__ __forceinline__ float silu_f(float z) {      // z * rcp(1+exp(-z))
    return z * __builtin_amdgcn_rcpf(1.0f + __expf(-z));
}
__device__ __forceinline__ u32 pack_bf16(float lo, float hi) {
    __hip_bfloat162 p = __float22bfloat162_rn(float2{lo, hi});
    u32 r;
    __builtin_memcpy(&r, &p, 4);
    return r;
}

// ---------- W3 (8192x64 f32) -> bf16 MFMA B-fragments in ws (1 MB) ----------
// frag id m = (lt*2 + kk)*4 + ns ; lane holds W3[kb + (lane>>4)*8 + j][ns*16 + (lane&15)]
__global__ __launch_bounds__(256) void w3_prep(const float* __restrict__ W3,
                                               u32* __restrict__ wsf) {
    const int tid  = blockIdx.x * 256 + threadIdx.x;    // 65536 threads
    const int lane = tid & 63;
    const int m    = tid >> 6;                          // 0..1023
    const int ns   = m & 3;
    const int kb   = (m >> 2) * 32;                     // lt*64 + kk*32
    const int row0 = kb + ((lane >> 4) << 3);
    const int col  = (ns << 4) + (lane & 15);
    u32 q[4];
    #pragma unroll
    for (int jj = 0; jj < 4; ++jj) {
        const float lo = W3[(size_t)(row0 + 2 * jj)     * DD + col];
        const float hi = W3[(size_t)(row0 + 2 * jj + 1) * DD + col];
        q[jj] = f2bf(lo) | (f2bf(hi) << 16);
    }
    i32x4 v; v.x = q[0]; v.y = q[1]; v.z = q[2]; v.w = q[3];
    *(i32x4*)(wsf + (size_t)m * 256 + (lane << 2)) = v;
}

// ---------------------------- fused main kernel ----------------------------
// NOTE: no min-waves hint — __launch_bounds__(256, 8) forced the ~40-float W1
// state into scratch (round 4: WRITE_SIZE 4->90 MB, VALUBusy 49->21%).
// USE_PART: write acc fragments to ws partial buffer (no memset, no atomics).
template<bool USE_WS, bool USE_PART>
__global__ __launch_bounds__(NT_MAIN) void htfe_main(
    const float* __restrict__ x, const int* __restrict__ start_L,
    const int* __restrict__ idx_C, const float* __restrict__ W1,
    const float* __restrict__ b1, const float* __restrict__ W3,
    const u32* __restrict__ wsf, float* __restrict__ part,
    float* __restrict__ out)
{
    __shared__ __align__(16) float xvbuf[LT_PER][PPB * XSTRIDE]; // 12 KB gathered x
    __shared__ __align__(16) u32   hbuf[2][PPB * DD / 2];        // 2x2 KB bf16 h, swizzled
    __shared__ int sStart[PPB];
    __shared__ int sCi[PPB][PC];

    const int t    = threadIdx.x;
    const int lane = t & 63;
    const int w    = t >> 6;                 // wave = N-slice 0..3
    const int blk  = blockIdx.x;
    const int split = blk & (KSPLIT - 1);
    const int mb    = blk >> 3;              // /KSPLIT
    const int b     = mb >> 2;               // NPP/PPB = 4 groups
    const int p0    = (mb & 3) * PPB;
    const int lt0   = split * LT_PER;

    if (t < PPB) sStart[t] = start_L[b * NPP + p0 + t];
    if (t < PPB * PC) {
        const int pp = t >> 3, c = t & 7;
        sCi[pp][c] = idx_C[(size_t)((b * NPP + p0 + pp) << 3) + c];
    }
    __syncthreads();

    // ----- per-lane hoisted W1 slice + folded constant bias -----
    const int p  = lane >> 2;                       // phase-A patch
    const int d0 = (w << 4) + ((lane & 3) << 2);    // phase-A d base (4 values)
    float w1x[PC][4], w1t[4], cb[4];
    {
        const f32x4 vt = *(const f32x4*)(W1 + PC * DD + d0);
        const f32x4 vb = *(const f32x4*)(b1 + d0);
        const float st = (float)sStart[p] * TSTEP;  // start never wraps: start <= L-PL
        #pragma unroll
        for (int j = 0; j < 4; ++j) { w1t[j] = vt[j]; cb[j] = vb[j] + st * vt[j]; }
        #pragma unroll
        for (int c = 0; c < PC; ++c) {
            const f32x4 vx = *(const f32x4*)(W1 + c * DD + d0);
            const f32x4 vc = *(const f32x4*)(W1 + (PC + 1 + c) * DD + d0);
            const float cf = (float)sCi[p][c];
            #pragma unroll
            for (int j = 0; j < 4; ++j) { w1x[c][j] = vx[j]; cb[j] += cf * vc[j]; }
        }
    }

    // ----- stage all gathered x values for this block's lt range -----
    for (int i = t; i < LT_PER * PPB * PC; i += NT_MAIN) {
        const int lt = i >> 7;
        const int pp = (i >> 3) & 15;
        const int c  = i & 7;
        xvbuf[lt][pp * XSTRIDE + c] =
            x[((size_t)b * LL + (size_t)(sStart[pp] + lt0 + lt)) * CC + sCi[pp][c]];
    }
    __syncthreads();

    // swizzled LDS addresses: byte = (p*128 + d*2) ^ ((p&7)<<4)
    const int wrByte = ((p << 7) + (d0 << 1)) ^ ((p & 7) << 4);
    const int pB    = lane & 15;
    const int rbase = (pB << 7) + ((lane >> 4) << 4);
    const int swzB  = (pB & 7) << 4;
    const int rd0 = rbase ^ swzB;
    const int rd1 = (rbase + 64) ^ swzB;

    f32x4 acc = {0.f, 0.f, 0.f, 0.f};
    const u32* bsrc = wsf + (size_t)(lt0 * 8 + w) * 256 + (lane << 2);

    for (int lt = 0; lt < LT_PER; ++lt) {
        const int cur = lt & 1;
        // ---- phase A: 4 h values per lane (9 fma + cheap silu, all-register) ----
        const float tl = (float)(lt0 + lt) * TSTEP;
        const float* xvp = &xvbuf[lt][p * XSTRIDE];
        const f32x4 xa = *(const f32x4*)xvp;
        const f32x4 xc = *(const f32x4*)(xvp + 4);
        float hh[4];
        #pragma unroll
        for (int j = 0; j < 4; ++j) {
            float a = cb[j] + tl * w1t[j];
            a += xa.x * w1x[0][j]; a += xa.y * w1x[1][j];
            a += xa.z * w1x[2][j]; a += xa.w * w1x[3][j];
            a += xc.x * w1x[4][j]; a += xc.y * w1x[5][j];
            a += xc.z * w1x[6][j]; a += xc.w * w1x[7][j];
            hh[j] = silu_f(a);
        }
        const u32 pk0 = pack_bf16(hh[0], hh[1]);
        const u32 pk1 = pack_bf16(hh[2], hh[3]);
        char* hbB = (char*)&hbuf[cur][0];
        *(uint2*)(hbB + wrByte) = make_uint2(pk0, pk1);

        // ---- B-fragments (issued before the barrier to hide latency) ----
        i32x4 bf0, bf1;
        if (USE_WS) {
            bf0 = *(const i32x4*)(bsrc);
            bf1 = *(const i32x4*)(bsrc + 1024);
            bsrc += 2048;
        } else {
            const int row0 = (lt0 + lt) * DD + ((lane >> 4) << 3);
            const int colW = (w << 4) + pB;
            u32 q[8];
            #pragma unroll
            for (int jj = 0; jj < 4; ++jj) {
                q[jj]     = f2bf(W3[(size_t)(row0 + 2*jj)      * DD + colW]) |
                            (f2bf(W3[(size_t)(row0 + 2*jj + 1) * DD + colW]) << 16);
                q[4 + jj] = f2bf(W3[(size_t)(row0 + 32 + 2*jj)      * DD + colW]) |
                            (f2bf(W3[(size_t)(row0 + 32 + 2*jj + 1) * DD + colW]) << 16);
            }
            bf0.x = q[0]; bf0.y = q[1]; bf0.z = q[2]; bf0.w = q[3];
            bf1.x = q[4]; bf1.y = q[5]; bf1.z = q[6]; bf1.w = q[7];
        }

        __syncthreads();   // h tile ready (double-buffered -> 1 barrier per lt)

        // ---- phase B: A-frags from swizzled LDS, 2 MFMAs ----
        const i32x4 af0 = *(const i32x4*)(hbB + rd0);
        const i32x4 af1 = *(const i32x4*)(hbB + rd1);
        if (!USE_WS) asm volatile("s_nop 3" ::);   // VALU-write -> MFMA-read hazard
        asm("v_mfma_f32_16x16x32_bf16 %0, %1, %2, %0" : "+v"(acc) : "v"(af0), "v"(bf0));
        asm("v_mfma_f32_16x16x32_bf16 %0, %1, %2, %0" : "+v"(acc) : "v"(af1), "v"(bf1));
    }

    asm volatile("s_nop 7\ns_nop 7\ns_nop 7" ::);  // MFMA-write -> read hazard
    if (USE_PART) {
        // coalesced fragment-layout partial store: one dwordx4 per lane
        float* pdst = part + ((((size_t)mb * KSPLIT + split) * 4 + w) * 64 + lane) * 4;
        *(f32x4*)pdst = acc;
    } else {
        #pragma unroll
        for (int r = 0; r < 4; ++r) {
            const int prow = ((lane >> 4) << 2) + r;   // verified C/D layout (m89/m91)
            atomicAdd(out + (size_t)(b * NPP + p0 + prow) * DD + (w << 4) + pB, acc[r]);
        }
    }
}

// ------------- partial reduce + bias + SiLU (writes out exactly once) -------------
__global__ __launch_bounds__(256) void finish_reduce(const float* __restrict__ part,
                                                     const float* __restrict__ b3,
                                                     float* __restrict__ out) {
    const int tid  = blockIdx.x * 256 + threadIdx.x;   // 65536 threads
    const int lane = tid & 63;
    const int w    = (tid >> 6) & 3;
    const int mb   = tid >> 8;
    const float* src = part + (((size_t)mb * KSPLIT * 4) + w) * 256 + (lane << 2);
    f32x4 s = {0.f, 0.f, 0.f, 0.f};
    #pragma unroll
    for (int split = 0; split < KSPLIT; ++split) {
        const f32x4 v = *(const f32x4*)(src + (size_t)split * 1024);
        s.x += v.x; s.y += v.y; s.z += v.z; s.w += v.w;
    }
    const int b   = mb >> 2;
    const int p0  = (mb & 3) * PPB;
    const int col = (w << 4) + (lane & 15);
    const float bias = b3[col];
    #pragma unroll
    for (int r = 0; r < 4; ++r) {
        const int prow = p0 + ((lane >> 4) << 2) + r;
        out[(size_t)(b * NPP + prow) * DD + col] = silu_f(s[r] + bias);
    }
}

// --------------------------- bias + SiLU epilogue (fallback) ---------------------------
__global__ __launch_bounds__(256) void finish_silu(float* __restrict__ out,
                                                   const float* __restrict__ b3) {
    const int i = blockIdx.x * 256 + threadIdx.x;   // 65536 threads x 4 elems
    const int base = i << 2;
    f32x4 v = *(f32x4*)(out + base);
    const f32x4 bb = *(const f32x4*)(b3 + (base & 63));
    #pragma unroll
    for (int j = 0; j < 4; ++j) v[j] = silu_f(v[j] + bb[j]);
    *(f32x4*)(out + base) = v;
}

extern "C" void kernel_launch(void* const* d_in, const int* in_sizes, int n_in,
                              void* d_out, int out_size, void* d_ws, size_t ws_size,
                              hipStream_t stream) {
    // inputs: x, start_L, idx_C, W1, b1, W2(unused), b2(unused), W3, b3
    const float* x       = (const float*)d_in[0];
    const int*   start_L = (const int*)  d_in[1];
    const int*   idx_C   = (const int*)  d_in[2];
    const float* W1      = (const float*)d_in[3];
    const float* b1      = (const float*)d_in[4];
    const float* W3      = (const float*)d_in[7];
    const float* b3      = (const float*)d_in[8];
    float* out = (float*)d_out;
    u32*   wsf = (u32*)d_ws;
    float* part = (float*)(wsf + FRAG_U32);

    const int grid_main = BB * (NPP / PPB) * KSPLIT;   // 2048
    const bool ws_frag = ws_size >= (size_t)FRAG_U32 * 4;
    const bool ws_part = ws_size >= (size_t)FRAG_U32 * 4 + (size_t)PART_FLT * 4;

    if (ws_part) {
        // no memset, no atomics: partials -> reduce
        w3_prep<<<256, 256, 0, stream>>>(W3, wsf);
        htfe_main<true, true><<<grid_main, NT_MAIN, 0, stream>>>(
            x, start_L, idx_C, W1, b1, W3, wsf, part, out);
        finish_reduce<<<(BB * 4 * 256) / 256, 256, 0, stream>>>(part, b3, out);
    } else if (ws_frag) {
        (void)hipMemsetAsync(d_out, 0, (size_t)out_size * sizeof(float), stream);
        w3_prep<<<256, 256, 0, stream>>>(W3, wsf);
        htfe_main<true, false><<<grid_main, NT_MAIN, 0, stream>>>(
            x, start_L, idx_C, W1, b1, W3, wsf, part, out);
        finish_silu<<<(BB * NPP * DD / 4) / 256, 256, 0, stream>>>(out, b3);
    } else {
        (void)hipMemsetAsync(d_out, 0, (size_t)out_size * sizeof(float), stream);
        htfe_main<false, false><<<grid_main, NT_MAIN, 0, stream>>>(
            x, start_L, idx_C, W1, b1, W3, wsf, part, out);
        finish_silu<<<(BB * NPP * DD / 4) / 256, 256, 0, stream>>>(out, b3);
    }
}